// Round 7
// baseline (1295.704 us; speedup 1.0000x reference)
//
#include <hip/hip_runtime.h>
#include <hip/hip_bf16.h>

#define T_SEQ 4096
#define C_EMB 768
#define HEAD  64

typedef short short4v __attribute__((ext_vector_type(4)));
typedef float floatx4 __attribute__((ext_vector_type(4)));

static __device__ __forceinline__ float bf2f(short s) {
    unsigned u = ((unsigned)(unsigned short)s) << 16;
    return __uint_as_float(u);
}
static __device__ __forceinline__ short f2bf(float v) {
    __hip_bfloat16 h = __float2bfloat16(v);
    return *reinterpret_cast<short*>(&h);
}

// ---------------------------------------------------------------------------
// Kernel 1: QKV projection, pure VALU, fp32 in / fp32 accumulation.
// Block = 64 rows of x; thread (w = tid>>6, L = tid&63) owns row t=L,
// output cols w*16..w*16+15 for each of K/Q/V.
// ---------------------------------------------------------------------------
__global__ __launch_bounds__(256) void qkv_valu(
    const float* __restrict__ x,
    const float* __restrict__ Wk, const float* __restrict__ Wq,
    const float* __restrict__ Wv,
    const float* __restrict__ bk, const float* __restrict__ bq,
    const float* __restrict__ bv,
    float* __restrict__ K, float* __restrict__ Q, float* __restrict__ V) {
    __shared__ float Ws[3][32][64];   // W k-tile fp32 (24 KB)
    __shared__ float xsT[32][66];     // x k-tile transposed fp32 (8.25 KB)

    int tid = threadIdx.x;
    int w = tid >> 6, L = tid & 63;
    int row0 = blockIdx.x * 64;

    float acc[3][16];
#pragma unroll
    for (int g = 0; g < 3; ++g)
#pragma unroll
        for (int j = 0; j < 16; ++j) acc[g][j] = 0.f;

    for (int kc = 0; kc < 24; ++kc) {
        __syncthreads();   // previous tile fully consumed
        // stage W tile: 3*32*64 floats = 1536 float4, 6 per thread
#pragma unroll
        for (int i = 0; i < 6; ++i) {
            int l4 = tid + 256 * i;              // 0..1535
            int g = l4 >> 9;                     // /512
            int rem = l4 & 511;
            int k = rem >> 4, nq = rem & 15;
            const float* Wp = (g == 0) ? Wk : (g == 1) ? Wq : Wv;
            floatx4 f4 = *(const floatx4*)(Wp + (size_t)(kc * 32 + k) * 64 + nq * 4);
            *(floatx4*)&Ws[g][k][nq * 4] = f4;
        }
        // stage x tile transposed: 64 rows x 32 k = 512 float4, 2 per thread
#pragma unroll
        for (int i = 0; i < 2; ++i) {
            int l4 = tid + 256 * i;              // 0..511
            int t = l4 >> 3, kq = l4 & 7;
            floatx4 f4 = *(const floatx4*)(x + (size_t)(row0 + t) * C_EMB
                                             + kc * 32 + kq * 4);
#pragma unroll
            for (int q = 0; q < 4; ++q) xsT[kq * 4 + q][t] = f4[q];
        }
        __syncthreads();
        // accumulate
        for (int k = 0; k < 32; ++k) {
            float xv = xsT[k][L];
#pragma unroll
            for (int g = 0; g < 3; ++g) {
#pragma unroll
                for (int j4 = 0; j4 < 4; ++j4) {
                    floatx4 w4 = *(const floatx4*)&Ws[g][k][w * 16 + j4 * 4];
#pragma unroll
                    for (int q = 0; q < 4; ++q)
                        acc[g][j4 * 4 + q] += xv * w4[q];
                }
            }
        }
    }

    // epilogue: add bias, store fp32
#pragma unroll
    for (int g = 0; g < 3; ++g) {
        const float* bp = (g == 0) ? bk : (g == 1) ? bq : bv;
        float* dst = (g == 0) ? K : (g == 1) ? Q : V;
#pragma unroll
        for (int j = 0; j < 16; ++j) {
            int h = w * 16 + j;
            dst[(size_t)(row0 + L) * HEAD + h] = acc[g][j] + bp[h];
        }
    }
}

// ---------------------------------------------------------------------------
// Kernel 2: causal attention (roles swapped: wei[t][s] = k[t]·q[s]),
// pure VALU, coordinate-explicit masking, online softmax.
// Grid (64 t-tiles, 4 batches), 256 threads. Thread (w, L): t-row L,
// columns w*16..w*16+15 (s in phase 1, h in phase 3).
// OUTPUT: fp32 (reference output dtype).
// ---------------------------------------------------------------------------
__global__ __launch_bounds__(256) void attn_valu(
    const float* __restrict__ K, const float* __restrict__ Q,
    const float* __restrict__ V, float* __restrict__ out) {
    __shared__ float KsT[64][65];   // K tile transposed [h][t] (16.6 KB)
    __shared__ float Qs[64][64];    // Q tile fp32 [s][h]       (16 KB)
    __shared__ short Vs[64][64];    // V tile bf16 [s][h]       (8 KB)
    __shared__ float Ss[64][65];    // scores / P [t][s]        (16.6 KB)
    __shared__ float m_s[64], l_s[64], al_s[64];

    const float scale = 0.036084392f;   // 768^-0.5

    int tid = threadIdx.x;
    int w = tid >> 6, L = tid & 63;
    int tt = blockIdx.x, b = blockIdx.y;
    int t0 = tt * 64;

    // stage K tile transposed (once per block)
#pragma unroll
    for (int i = 0; i < 16; ++i) {
        int lin = tid + 256 * i;            // 0..4095
        int t = lin >> 6, h = lin & 63;
        KsT[h][t] = K[(size_t)(b * T_SEQ + t0 + t) * HEAD + h];
    }
    if (tid < 64) { m_s[tid] = -1e30f; l_s[tid] = 0.f; }

    float o[16];
#pragma unroll
    for (int j = 0; j < 16; ++j) o[j] = 0.f;

    for (int st = 0; st <= tt; ++st) {
        int s0 = st * 64;
        __syncthreads();   // A: prior phase-3 reads done (covers K staging too)
        // stage Q (fp32) and V (bf16) tiles
#pragma unroll
        for (int i = 0; i < 4; ++i) {
            int l4 = tid + 256 * i;          // 0..1023
            int r = l4 >> 4, c4 = l4 & 15;
            *(floatx4*)&Qs[r][c4 * 4] =
                *(const floatx4*)(Q + (size_t)(b * T_SEQ + s0 + r) * HEAD + c4 * 4);
            floatx4 vv = *(const floatx4*)(V + (size_t)(b * T_SEQ + s0 + r) * HEAD + c4 * 4);
            short4v vs;
#pragma unroll
            for (int q = 0; q < 4; ++q) vs[q] = f2bf(vv[q]);
            *(short4v*)&Vs[r][c4 * 4] = vs;
        }
        __syncthreads();   // B: tiles visible

        // phase 1: S[t=L][s=w*16+j] = dot64(K[t], Q[s])
#pragma unroll
        for (int j = 0; j < 16; ++j) {
            int s = w * 16 + j;
            float acc = 0.f;
#pragma unroll
            for (int hh = 0; hh < 16; ++hh) {
                floatx4 q4 = *(const floatx4*)&Qs[s][hh * 4];
#pragma unroll
                for (int q = 0; q < 4; ++q)
                    acc += KsT[hh * 4 + q][L] * q4[q];
            }
            Ss[L][s] = acc;
        }
        __syncthreads();   // C: S complete

        // phase 2 (wave 0 only): masked online softmax for row t = t0+L
        if (w == 0) {
            float mx = -1e30f;
            for (int s = 0; s < 64; ++s) {
                float z = Ss[L][s] * scale;
                bool ok = (s0 + s) <= (t0 + L);
                mx = fmaxf(mx, ok ? z : -1e30f);
            }
            float mold = m_s[L];
            float mn = fmaxf(mold, mx);
            float alpha = __expf(mold - mn);
            float sum = 0.f;
            for (int s = 0; s < 64; ++s) {
                float z = Ss[L][s] * scale;
                bool ok = (s0 + s) <= (t0 + L);
                float p = ok ? __expf(z - mn) : 0.f;
                Ss[L][s] = p;
                sum += p;
            }
            m_s[L] = mn;
            l_s[L] = l_s[L] * alpha + sum;
            al_s[L] = alpha;
        }
        __syncthreads();   // D: P, alpha ready

        // phase 3: O[t=L][h=w*16+j] update
        float alpha = al_s[L];
#pragma unroll
        for (int j = 0; j < 16; ++j) o[j] *= alpha;
        for (int s = 0; s < 64; ++s) {
            float p = Ss[L][s];
#pragma unroll
            for (int j4 = 0; j4 < 4; ++j4) {
                short4v v4 = *(const short4v*)&Vs[s][w * 16 + j4 * 4];
#pragma unroll
                for (int q = 0; q < 4; ++q)
                    o[j4 * 4 + q] += p * bf2f(v4[q]);
            }
        }
    }

    // epilogue: fp32 output
    float inv = 1.f / l_s[L];
#pragma unroll
    for (int j = 0; j < 16; ++j) {
        out[(size_t)(b * T_SEQ + t0 + L) * HEAD + w * 16 + j] = o[j] * inv;
    }
}

extern "C" void kernel_launch(void* const* d_in, const int* in_sizes, int n_in,
                              void* d_out, int out_size, void* d_ws, size_t ws_size,
                              hipStream_t stream) {
    // Robust input mapping by SIZE (host-side). Under both insertion order
    // {x,Wk,bk,Wq,bq,Wv,bv} and any key-sorted order, W's appear among
    // themselves as Wk,Wq,Wv and b's as bk,bq,bv.
    const int XSZ = 4 * T_SEQ * C_EMB;   // 12582912
    const int WSZ = C_EMB * HEAD;        // 49152
    const int BSZ = HEAD;                // 64
    const float* x = nullptr;
    const float* W[3] = {nullptr, nullptr, nullptr};
    const float* B[3] = {nullptr, nullptr, nullptr};
    int iw = 0, ib = 0;
    for (int i = 0; i < n_in; ++i) {
        if (in_sizes[i] == XSZ) x = (const float*)d_in[i];
        else if (in_sizes[i] == WSZ && iw < 3) W[iw++] = (const float*)d_in[i];
        else if (in_sizes[i] == BSZ && ib < 3) B[ib++] = (const float*)d_in[i];
    }

    float* ws = (float*)d_ws;
    float* K = ws;                                // [16384][64] fp32
    float* Q = K + (size_t)4 * T_SEQ * HEAD;      // [16384][64] fp32
    float* V = Q + (size_t)4 * T_SEQ * HEAD;      // [16384][64] fp32

    qkv_valu<<<256, 256, 0, stream>>>(x, W[0], W[1], W[2], B[0], B[1], B[2], K, Q, V);
    attn_valu<<<dim3(64, 4), 256, 0, stream>>>(K, Q, V, (float*)d_out);
}

// Round 8
// 246.882 us; speedup vs baseline: 5.2483x; 5.2483x over previous
//
#include <hip/hip_runtime.h>
#include <hip/hip_bf16.h>

#define T_SEQ 4096
#define C_EMB 768
#define HEAD  64

typedef short  short8  __attribute__((ext_vector_type(8)));
typedef float  floatx4 __attribute__((ext_vector_type(4)));

static __device__ __forceinline__ short f2bf(float v) {
    __hip_bfloat16 h = __float2bfloat16(v);
    return *reinterpret_cast<short*>(&h);
}

// ---------------------------------------------------------------------------
// Kernel 0: transpose+downcast fp32 W[768][64] -> bf16 Wt[g][n=64][k=768]
// ---------------------------------------------------------------------------
__global__ void wt_transpose_kernel(const float* __restrict__ Wk,
                                    const float* __restrict__ Wq,
                                    const float* __restrict__ Wv,
                                    short* __restrict__ Wt) {
    const int total = 3 * HEAD * C_EMB;
    for (int idx = blockIdx.x * blockDim.x + threadIdx.x; idx < total;
         idx += gridDim.x * blockDim.x) {
        int g   = idx / (HEAD * C_EMB);
        int rem = idx - g * (HEAD * C_EMB);
        int n   = rem / C_EMB;
        int k   = rem - n * C_EMB;
        const float* W = (g == 0) ? Wk : (g == 1) ? Wq : Wv;
        Wt[idx] = f2bf(W[k * HEAD + n]);
    }
}

// ---------------------------------------------------------------------------
// Kernel 1: QKV projection via MFMA. fp32 x -> bf16 A-frags in-register.
// 256 blocks x 4 waves; wave computes 16 rows x 192 cols (K|Q|V).
// Outputs bf16: Kb[t][h], Qb[t][h], Vt[b][h][t] (V pre-transposed).
// ---------------------------------------------------------------------------
__global__ __launch_bounds__(256) void qkv_mfma(
    const float* __restrict__ x, const short* __restrict__ Wt,
    const float* __restrict__ bk, const float* __restrict__ bq,
    const float* __restrict__ bv,
    short* __restrict__ Kb, short* __restrict__ Qb, short* __restrict__ Vt) {
    int tid  = threadIdx.x;
    int wave = tid >> 6, lane = tid & 63;
    int ln15 = lane & 15, quad = lane >> 4;
    int row  = blockIdx.x * 64 + wave * 16 + ln15;   // A-frag row (m = lane&15)

    floatx4 acc[12];
#pragma unroll
    for (int j = 0; j < 12; ++j) acc[j] = (floatx4){0.f, 0.f, 0.f, 0.f};

    const float* xrow = x + (size_t)row * C_EMB + quad * 8;
#pragma unroll 2
    for (int kc = 0; kc < 24; ++kc) {
        floatx4 f0 = *(const floatx4*)(xrow + kc * 32);
        floatx4 f1 = *(const floatx4*)(xrow + kc * 32 + 4);
        short8 a;
#pragma unroll
        for (int e = 0; e < 4; ++e) { a[e] = f2bf(f0[e]); a[4 + e] = f2bf(f1[e]); }
#pragma unroll
        for (int j = 0; j < 12; ++j) {
            int g  = j >> 2;
            int nl = (j & 3) * 16 + ln15;
            short8 bfr = *(const short8*)(Wt + ((size_t)(g * HEAD + nl)) * C_EMB
                                              + kc * 32 + quad * 8);
            acc[j] = __builtin_amdgcn_mfma_f32_16x16x32_bf16(a, bfr, acc[j], 0, 0, 0);
        }
    }

#pragma unroll
    for (int j = 0; j < 12; ++j) {
        int g  = j >> 2;
        int nl = (j & 3) * 16 + ln15;
        float bias = (g == 0 ? bk : g == 1 ? bq : bv)[nl];
#pragma unroll
        for (int r = 0; r < 4; ++r) {
            int grow = blockIdx.x * 64 + wave * 16 + quad * 4 + r;  // C/D row
            short hv = f2bf(acc[j][r] + bias);
            if (g == 0)      Kb[(size_t)grow * HEAD + nl] = hv;
            else if (g == 1) Qb[(size_t)grow * HEAD + nl] = hv;
            else {
                int b = grow >> 12, t = grow & 4095;
                Vt[((size_t)(b * HEAD + nl) << 12) + t] = hv;   // V transposed
            }
        }
    }
}

// ---------------------------------------------------------------------------
// Kernel 2: causal flash attention (roles swapped: wei[t][s]=k[t]·q[s]) via
// MFMA. grid (64 t-tiles, 4 batches), 4 waves x 16 t-rows. fp32 output.
// ---------------------------------------------------------------------------
__global__ __launch_bounds__(256) void attn_mfma(
    const short* __restrict__ Kb, const short* __restrict__ Qb,
    const short* __restrict__ Vt, float* __restrict__ out) {
    __shared__ __align__(16) short Qs[64][72];        // Q rows [s][h], pad +8
    __shared__ __align__(16) short Vs[64][72];        // V transposed [h][s_loc]
    __shared__ __align__(16) short Ps[4][16][72];     // per-wave P [t][s_loc]

    const float scale2 = 0.052058773f;   // 768^-0.5 * log2(e)
    const float NEGBIG = -1e30f;

    int tid  = threadIdx.x;
    int wave = tid >> 6, lane = tid & 63;
    int ln15 = lane & 15, quad = lane >> 4;
    int tt = blockIdx.x, b = blockIdx.y;
    int t0 = tt * 64;

    // K A-fragments for this wave's 16 t-rows (resident whole kernel)
    const short* kp = Kb + ((size_t)(b * T_SEQ + t0 + wave * 16 + ln15)) * HEAD + quad * 8;
    short8 ak0 = *(const short8*)kp;
    short8 ak1 = *(const short8*)(kp + 32);

    float m[4], l[4];
    floatx4 o[4];
#pragma unroll
    for (int r = 0; r < 4; ++r) { m[r] = NEGBIG; l[r] = 0.f; }
#pragma unroll
    for (int j = 0; j < 4; ++j) o[j] = (floatx4){0.f, 0.f, 0.f, 0.f};

    for (int st = 0; st <= tt; ++st) {
        int s0 = st * 64;
        __syncthreads();   // prior iteration's reads of Qs/Vs complete
#pragma unroll
        for (int i = 0; i < 2; ++i) {
            int slot = tid + i * 256;          // 512 slots = 64 rows x 8 chunks
            int rr = slot >> 3, cc = slot & 7;
            *(short8*)&Qs[rr][cc * 8] =
                *(const short8*)(Qb + ((size_t)(b * T_SEQ + s0 + rr)) * HEAD + cc * 8);
            *(short8*)&Vs[rr][cc * 8] =
                *(const short8*)(Vt + ((size_t)(b * HEAD + rr) << 12) + s0 + cc * 8);
        }
        __syncthreads();

        // S = K . Q^T  (m = t rows, n = s cols), 4 n-blocks x 2 k-steps
        floatx4 sacc[4];
#pragma unroll
        for (int nb = 0; nb < 4; ++nb) {
            short8 bq0 = *(const short8*)&Qs[nb * 16 + ln15][quad * 8];
            short8 bq1 = *(const short8*)&Qs[nb * 16 + ln15][32 + quad * 8];
            floatx4 z4 = (floatx4){0.f, 0.f, 0.f, 0.f};
            z4 = __builtin_amdgcn_mfma_f32_16x16x32_bf16(ak0, bq0, z4, 0, 0, 0);
            z4 = __builtin_amdgcn_mfma_f32_16x16x32_bf16(ak1, bq1, z4, 0, 0, 0);
            sacc[nb] = z4;
        }

        // online softmax in C/D layout: row = quad*4+r, col = nb*16+ln15
        float p[4][4];
        float vm[4], rs[4], alpha[4];
        bool diag = (st == tt);
#pragma unroll
        for (int r = 0; r < 4; ++r) {
            int tg = t0 + wave * 16 + quad * 4 + r;
            float best = NEGBIG;
#pragma unroll
            for (int nb = 0; nb < 4; ++nb) {
                float z = sacc[nb][r] * scale2;
                if (diag) {
                    int sg = s0 + nb * 16 + ln15;
                    if (sg > tg) z = NEGBIG;
                }
                p[nb][r] = z;
                best = fmaxf(best, z);
            }
            vm[r] = best;
        }
#pragma unroll
        for (int mask = 1; mask <= 8; mask <<= 1) {
#pragma unroll
            for (int r = 0; r < 4; ++r)
                vm[r] = fmaxf(vm[r], __shfl_xor(vm[r], mask, 64));
        }
#pragma unroll
        for (int r = 0; r < 4; ++r) {
            float mn = fmaxf(m[r], vm[r]);
            alpha[r] = exp2f(m[r] - mn);
            m[r] = mn;
            float rsum = 0.f;
#pragma unroll
            for (int nb = 0; nb < 4; ++nb) {
                p[nb][r] = exp2f(p[nb][r] - mn);
                rsum += p[nb][r];
            }
            rs[r] = rsum;
        }
#pragma unroll
        for (int mask = 1; mask <= 8; mask <<= 1) {
#pragma unroll
            for (int r = 0; r < 4; ++r)
                rs[r] += __shfl_xor(rs[r], mask, 64);
        }
#pragma unroll
        for (int r = 0; r < 4; ++r) l[r] = l[r] * alpha[r] + rs[r];
#pragma unroll
        for (int j = 0; j < 4; ++j) {
#pragma unroll
            for (int r = 0; r < 4; ++r) o[j][r] *= alpha[r];
        }

        // P: C/D layout -> wave-local LDS -> A layout
#pragma unroll
        for (int r = 0; r < 4; ++r) {
#pragma unroll
            for (int nb = 0; nb < 4; ++nb)
                Ps[wave][quad * 4 + r][nb * 16 + ln15] = f2bf(p[nb][r]);
        }
        // wave-local cross-lane LDS round trip: drain DS queue before reads
        __asm__ volatile("s_waitcnt lgkmcnt(0)" ::: "memory");
        short8 ap0 = *(const short8*)&Ps[wave][ln15][quad * 8];
        short8 ap1 = *(const short8*)&Ps[wave][ln15][32 + quad * 8];

        // O += P . V   (contraction over s; B[k=s][n=h] = Vs[h][s])
#pragma unroll
        for (int j = 0; j < 4; ++j) {
            short8 bv0 = *(const short8*)&Vs[j * 16 + ln15][quad * 8];
            short8 bv1 = *(const short8*)&Vs[j * 16 + ln15][32 + quad * 8];
            o[j] = __builtin_amdgcn_mfma_f32_16x16x32_bf16(ap0, bv0, o[j], 0, 0, 0);
            o[j] = __builtin_amdgcn_mfma_f32_16x16x32_bf16(ap1, bv1, o[j], 0, 0, 0);
        }
    }

    // epilogue: normalize, store fp32
#pragma unroll
    for (int r = 0; r < 4; ++r) {
        int tg = t0 + wave * 16 + quad * 4 + r;
        float inv = 1.f / l[r];
#pragma unroll
        for (int j = 0; j < 4; ++j) {
            out[((size_t)(b * T_SEQ + tg)) * HEAD + j * 16 + ln15] = o[j][r] * inv;
        }
    }
}

extern "C" void kernel_launch(void* const* d_in, const int* in_sizes, int n_in,
                              void* d_out, int out_size, void* d_ws, size_t ws_size,
                              hipStream_t stream) {
    // Size-based input mapping (order-robust; W's and b's keep internal order)
    const int XSZ = 4 * T_SEQ * C_EMB;   // 12582912
    const int WSZ = C_EMB * HEAD;        // 49152
    const int BSZ = HEAD;                // 64
    const float* x = nullptr;
    const float* W[3] = {nullptr, nullptr, nullptr};
    const float* B[3] = {nullptr, nullptr, nullptr};
    int iw = 0, ib = 0;
    for (int i = 0; i < n_in; ++i) {
        if (in_sizes[i] == XSZ) x = (const float*)d_in[i];
        else if (in_sizes[i] == WSZ && iw < 3) W[iw++] = (const float*)d_in[i];
        else if (in_sizes[i] == BSZ && ib < 3) B[ib++] = (const float*)d_in[i];
    }

    short* ws = (short*)d_ws;
    short* Kb = ws;                               // [16384][64] bf16
    short* Qb = Kb + (size_t)4 * T_SEQ * HEAD;    // [16384][64] bf16
    short* Vt = Qb + (size_t)4 * T_SEQ * HEAD;    // [4][64][4096] bf16
    short* Wt = Vt + (size_t)4 * HEAD * T_SEQ;    // [3][64][768] bf16

    wt_transpose_kernel<<<96, 256, 0, stream>>>(W[0], W[1], W[2], Wt);
    qkv_mfma<<<256, 256, 0, stream>>>(x, Wt, B[0], B[1], B[2], Kb, Qb, Vt);
    attn_mfma<<<dim3(64, 4), 256, 0, stream>>>(Kb, Qb, Vt, (float*)d_out);
}

// Round 9
// 216.978 us; speedup vs baseline: 5.9716x; 1.1378x over previous
//
#include <hip/hip_runtime.h>
#include <hip/hip_bf16.h>

#define T_SEQ 4096
#define C_EMB 768
#define HEAD  64

typedef short  short8  __attribute__((ext_vector_type(8)));
typedef float  floatx4 __attribute__((ext_vector_type(4)));

static __device__ __forceinline__ short f2bf(float v) {
    __hip_bfloat16 h = __float2bfloat16(v);
    return *reinterpret_cast<short*>(&h);
}
static __device__ __forceinline__ float bf2f(short s) {
    unsigned u = ((unsigned)(unsigned short)s) << 16;
    return __uint_as_float(u);
}

// ---------------------------------------------------------------------------
// Kernel 0: transpose+downcast fp32 W[768][64] -> bf16 Wt[g][n=64][k=768]
// ---------------------------------------------------------------------------
__global__ void wt_transpose_kernel(const float* __restrict__ Wk,
                                    const float* __restrict__ Wq,
                                    const float* __restrict__ Wv,
                                    short* __restrict__ Wt) {
    const int total = 3 * HEAD * C_EMB;
    for (int idx = blockIdx.x * blockDim.x + threadIdx.x; idx < total;
         idx += gridDim.x * blockDim.x) {
        int g   = idx / (HEAD * C_EMB);
        int rem = idx - g * (HEAD * C_EMB);
        int n   = rem / C_EMB;
        int k   = rem - n * C_EMB;
        const float* W = (g == 0) ? Wk : (g == 1) ? Wq : Wv;
        Wt[idx] = f2bf(W[k * HEAD + n]);
    }
}

// ---------------------------------------------------------------------------
// Kernel 1: QKV projection via MFMA. 256 blocks x 768 thr (12 waves):
// wave = (g = wave>>2) x (rowgrp = wave&3). Each wave: 16 rows x 64 cols of
// ONE output matrix -> 3072 waves = 3/SIMD (latency hiding). Sibling g-waves
// share x loads via L1.
// ---------------------------------------------------------------------------
__global__ __launch_bounds__(768) void qkv_mfma(
    const float* __restrict__ x, const short* __restrict__ Wt,
    const float* __restrict__ bk, const float* __restrict__ bq,
    const float* __restrict__ bv,
    short* __restrict__ Kb, short* __restrict__ Qb, short* __restrict__ Vt) {
    int tid  = threadIdx.x;
    int wave = tid >> 6, lane = tid & 63;
    int ln15 = lane & 15, quad = lane >> 4;
    int g = wave >> 2, rowgrp = wave & 3;
    int row = blockIdx.x * 64 + rowgrp * 16 + ln15;   // A-frag row (m=lane&15)

    floatx4 acc[4];
#pragma unroll
    for (int j = 0; j < 4; ++j) acc[j] = (floatx4){0.f, 0.f, 0.f, 0.f};

    const float* xrow = x + (size_t)row * C_EMB + quad * 8;
    const short* wbase = Wt + (size_t)g * HEAD * C_EMB;
#pragma unroll 2
    for (int kc = 0; kc < 24; ++kc) {
        floatx4 f0 = *(const floatx4*)(xrow + kc * 32);
        floatx4 f1 = *(const floatx4*)(xrow + kc * 32 + 4);
        short8 a;
#pragma unroll
        for (int e = 0; e < 4; ++e) { a[e] = f2bf(f0[e]); a[4 + e] = f2bf(f1[e]); }
#pragma unroll
        for (int j = 0; j < 4; ++j) {
            int nl = j * 16 + ln15;
            short8 bfr = *(const short8*)(wbase + (size_t)nl * C_EMB
                                              + kc * 32 + quad * 8);
            acc[j] = __builtin_amdgcn_mfma_f32_16x16x32_bf16(a, bfr, acc[j], 0, 0, 0);
        }
    }

    const float* bp = (g == 0) ? bk : (g == 1) ? bq : bv;
#pragma unroll
    for (int j = 0; j < 4; ++j) {
        int nl = j * 16 + ln15;
        float bias = bp[nl];
#pragma unroll
        for (int r = 0; r < 4; ++r) {
            int grow = blockIdx.x * 64 + rowgrp * 16 + quad * 4 + r;  // C/D row
            short hv = f2bf(acc[j][r] + bias);
            if (g == 0)      Kb[(size_t)grow * HEAD + nl] = hv;
            else if (g == 1) Qb[(size_t)grow * HEAD + nl] = hv;
            else {
                int b = grow >> 12, t = grow & 4095;
                Vt[((size_t)(b * HEAD + nl) << 12) + t] = hv;   // V transposed
            }
        }
    }
}

// ---------------------------------------------------------------------------
// Kernel 2: split-s causal flash attention partial. Block = (t-tile tt,
// s-chunk c, batch b). Chunk c covers s-tiles [32c, min(32c+31, tt)].
// blockIdx.x in [0,96): bx<32 -> (tt=bx, c=0); else j=bx-32, tt=32+(j>>1),
// c=j&1. Register-prefetch double-buffer on the Q/V staging.
// Writes unnormalized O (bf16) + m,l (fp32) partials.
// ---------------------------------------------------------------------------
__global__ __launch_bounds__(256) void attn_part(
    const short* __restrict__ Kb, const short* __restrict__ Qb,
    const short* __restrict__ Vt, short* __restrict__ Opart,
    float* __restrict__ mpart, float* __restrict__ lpart) {
    __shared__ __align__(16) short Qs[64][72];        // Q rows [s][h], pad +8
    __shared__ __align__(16) short Vs[64][72];        // V transposed [h][s_loc]
    __shared__ __align__(16) short Ps[4][16][72];     // per-wave P [t][s_loc]

    const float scale2 = 0.052058773f;   // 768^-0.5 * log2(e)
    const float NEGBIG = -1e30f;

    int tid  = threadIdx.x;
    int wave = tid >> 6, lane = tid & 63;
    int ln15 = lane & 15, quad = lane >> 4;
    int bx = blockIdx.x, b = blockIdx.y;
    int tt, c;
    if (bx < 32) { tt = bx; c = 0; }
    else { int j = bx - 32; tt = 32 + (j >> 1); c = j & 1; }
    int t0 = tt * 64;
    int lo = c * 32;
    int hi = min(c * 32 + 31, tt);

    // K A-fragments for this wave's 16 t-rows (resident whole kernel)
    const short* kp = Kb + ((size_t)(b * T_SEQ + t0 + wave * 16 + ln15)) * HEAD + quad * 8;
    short8 ak0 = *(const short8*)kp;
    short8 ak1 = *(const short8*)(kp + 32);

    float m[4], l[4];
    floatx4 o[4];
#pragma unroll
    for (int r = 0; r < 4; ++r) { m[r] = NEGBIG; l[r] = 0.f; }
#pragma unroll
    for (int j = 0; j < 4; ++j) o[j] = (floatx4){0.f, 0.f, 0.f, 0.f};

    // staging slots for this thread
    int rr[2], cc[2];
    short8 qpf[2], vpf[2];
#pragma unroll
    for (int i = 0; i < 2; ++i) {
        int slot = tid + i * 256;          // 512 slots = 64 rows x 8 chunks
        rr[i] = slot >> 3; cc[i] = slot & 7;
        int s0 = lo * 64;
        qpf[i] = *(const short8*)(Qb + ((size_t)(b * T_SEQ + s0 + rr[i])) * HEAD + cc[i] * 8);
        vpf[i] = *(const short8*)(Vt + ((size_t)(b * HEAD + rr[i]) << 12) + s0 + cc[i] * 8);
    }

    for (int st = lo; st <= hi; ++st) {
        int s0 = st * 64;
        __syncthreads();   // prior iteration's reads of Qs/Vs complete
#pragma unroll
        for (int i = 0; i < 2; ++i) {
            *(short8*)&Qs[rr[i]][cc[i] * 8] = qpf[i];
            *(short8*)&Vs[rr[i]][cc[i] * 8] = vpf[i];
        }
        // issue next tile's loads (clamped on last iter; overlaps compute)
        int sn = ((st < hi) ? (st + 1) : st) * 64;
        short8 qnx[2], vnx[2];
#pragma unroll
        for (int i = 0; i < 2; ++i) {
            qnx[i] = *(const short8*)(Qb + ((size_t)(b * T_SEQ + sn + rr[i])) * HEAD + cc[i] * 8);
            vnx[i] = *(const short8*)(Vt + ((size_t)(b * HEAD + rr[i]) << 12) + sn + cc[i] * 8);
        }
        __syncthreads();

        // S = K . Q^T  (m = t rows, n = s cols), 4 n-blocks x 2 k-steps
        floatx4 sacc[4];
#pragma unroll
        for (int nb = 0; nb < 4; ++nb) {
            short8 bq0 = *(const short8*)&Qs[nb * 16 + ln15][quad * 8];
            short8 bq1 = *(const short8*)&Qs[nb * 16 + ln15][32 + quad * 8];
            floatx4 z4 = (floatx4){0.f, 0.f, 0.f, 0.f};
            z4 = __builtin_amdgcn_mfma_f32_16x16x32_bf16(ak0, bq0, z4, 0, 0, 0);
            z4 = __builtin_amdgcn_mfma_f32_16x16x32_bf16(ak1, bq1, z4, 0, 0, 0);
            sacc[nb] = z4;
        }

        // online softmax in C/D layout: row = quad*4+r, col = nb*16+ln15
        float p[4][4];
        float vm[4], rs[4], alpha[4];
        bool diag = (st == tt);
#pragma unroll
        for (int r = 0; r < 4; ++r) {
            int tg = t0 + wave * 16 + quad * 4 + r;
            float best = NEGBIG;
#pragma unroll
            for (int nb = 0; nb < 4; ++nb) {
                float z = sacc[nb][r] * scale2;
                if (diag) {
                    int sg = s0 + nb * 16 + ln15;
                    if (sg > tg) z = NEGBIG;
                }
                p[nb][r] = z;
                best = fmaxf(best, z);
            }
            vm[r] = best;
        }
#pragma unroll
        for (int mask = 1; mask <= 8; mask <<= 1) {
#pragma unroll
            for (int r = 0; r < 4; ++r)
                vm[r] = fmaxf(vm[r], __shfl_xor(vm[r], mask, 64));
        }
#pragma unroll
        for (int r = 0; r < 4; ++r) {
            float mn = fmaxf(m[r], vm[r]);
            alpha[r] = exp2f(m[r] - mn);
            m[r] = mn;
            float rsum = 0.f;
#pragma unroll
            for (int nb = 0; nb < 4; ++nb) {
                p[nb][r] = exp2f(p[nb][r] - mn);
                rsum += p[nb][r];
            }
            rs[r] = rsum;
        }
#pragma unroll
        for (int mask = 1; mask <= 8; mask <<= 1) {
#pragma unroll
            for (int r = 0; r < 4; ++r)
                rs[r] += __shfl_xor(rs[r], mask, 64);
        }
#pragma unroll
        for (int r = 0; r < 4; ++r) l[r] = l[r] * alpha[r] + rs[r];
#pragma unroll
        for (int j = 0; j < 4; ++j) {
#pragma unroll
            for (int r = 0; r < 4; ++r) o[j][r] *= alpha[r];
        }

        // P: C/D layout -> wave-local LDS -> A layout
#pragma unroll
        for (int r = 0; r < 4; ++r) {
#pragma unroll
            for (int nb = 0; nb < 4; ++nb)
                Ps[wave][quad * 4 + r][nb * 16 + ln15] = f2bf(p[nb][r]);
        }
        __asm__ volatile("s_waitcnt lgkmcnt(0)" ::: "memory");
        short8 ap0 = *(const short8*)&Ps[wave][ln15][quad * 8];
        short8 ap1 = *(const short8*)&Ps[wave][ln15][32 + quad * 8];

        // O += P . V   (contraction over s; B[k=s][n=h] = Vs[h][s])
#pragma unroll
        for (int j = 0; j < 4; ++j) {
            short8 bv0 = *(const short8*)&Vs[j * 16 + ln15][quad * 8];
            short8 bv1 = *(const short8*)&Vs[j * 16 + ln15][32 + quad * 8];
            o[j] = __builtin_amdgcn_mfma_f32_16x16x32_bf16(ap0, bv0, o[j], 0, 0, 0);
            o[j] = __builtin_amdgcn_mfma_f32_16x16x32_bf16(ap1, bv1, o[j], 0, 0, 0);
        }
#pragma unroll
        for (int i = 0; i < 2; ++i) { qpf[i] = qnx[i]; vpf[i] = vnx[i]; }
    }

    // write partials: O unnormalized (bf16), m/l (fp32, wave-uniform per row)
#pragma unroll
    for (int r = 0; r < 4; ++r) {
        int t = t0 + wave * 16 + quad * 4 + r;
        size_t rowidx = ((size_t)(c * 4 + b)) * T_SEQ + t;
        if (ln15 == 0) { mpart[rowidx] = m[r]; lpart[rowidx] = l[r]; }
#pragma unroll
        for (int j = 0; j < 4; ++j)
            Opart[rowidx * HEAD + j * 16 + ln15] = f2bf(o[j][r]);
    }
}

// ---------------------------------------------------------------------------
// Kernel 3: merge <=2 partials per row -> fp32 out.
// ---------------------------------------------------------------------------
__global__ __launch_bounds__(256) void attn_merge(
    const short* __restrict__ Opart, const float* __restrict__ mpart,
    const float* __restrict__ lpart, float* __restrict__ out) {
    int idx = blockIdx.x * 256 + threadIdx.x;       // 0 .. 1048575
    int tg = idx >> 6, h = idx & 63;
    int b = tg >> 12, t = tg & 4095;
    int tt = t >> 6;
    size_t r0 = ((size_t)(0 * 4 + b)) * T_SEQ + t;
    float m0 = mpart[r0], l0 = lpart[r0];
    float o0 = bf2f(Opart[r0 * HEAD + h]);
    if (tt < 32) {
        out[idx] = o0 / l0;
    } else {
        size_t r1 = ((size_t)(1 * 4 + b)) * T_SEQ + t;
        float m1 = mpart[r1], l1 = lpart[r1];
        float o1 = bf2f(Opart[r1 * HEAD + h]);
        float M = fmaxf(m0, m1);
        float w0 = exp2f(m0 - M), w1 = exp2f(m1 - M);
        out[idx] = (o0 * w0 + o1 * w1) / (l0 * w0 + l1 * w1);
    }
}

extern "C" void kernel_launch(void* const* d_in, const int* in_sizes, int n_in,
                              void* d_out, int out_size, void* d_ws, size_t ws_size,
                              hipStream_t stream) {
    // Size-based input mapping (order-robust; W's and b's keep internal order)
    const int XSZ = 4 * T_SEQ * C_EMB;   // 12582912
    const int WSZ = C_EMB * HEAD;        // 49152
    const int BSZ = HEAD;                // 64
    const float* x = nullptr;
    const float* W[3] = {nullptr, nullptr, nullptr};
    const float* B[3] = {nullptr, nullptr, nullptr};
    int iw = 0, ib = 0;
    for (int i = 0; i < n_in; ++i) {
        if (in_sizes[i] == XSZ) x = (const float*)d_in[i];
        else if (in_sizes[i] == WSZ && iw < 3) W[iw++] = (const float*)d_in[i];
        else if (in_sizes[i] == BSZ && ib < 3) B[ib++] = (const float*)d_in[i];
    }

    short* ws = (short*)d_ws;
    short* Kb = ws;                               // [16384][64] bf16   2 MB
    short* Qb = Kb + (size_t)4 * T_SEQ * HEAD;    // [16384][64] bf16   2 MB
    short* Vt = Qb + (size_t)4 * T_SEQ * HEAD;    // [4][64][4096] bf16 2 MB
    short* Wt = Vt + (size_t)4 * HEAD * T_SEQ;    // [3][64][768] bf16  288 KB
    short* Opart = Wt + (size_t)3 * HEAD * C_EMB; // [2][4][4096][64]   4.2 MB
    float* mpart = (float*)(Opart + (size_t)2 * 4 * T_SEQ * HEAD); // 128 KB
    float* lpart = mpart + (size_t)2 * 4 * T_SEQ;                  // 128 KB

    wt_transpose_kernel<<<96, 256, 0, stream>>>(W[0], W[1], W[2], Wt);
    qkv_mfma<<<256, 768, 0, stream>>>(x, Wt, B[0], B[1], B[2], Kb, Qb, Vt);
    attn_part<<<dim3(96, 4), 256, 0, stream>>>(Kb, Qb, Vt, Opart, mpart, lpart);
    attn_merge<<<4096, 256, 0, stream>>>(Opart, mpart, lpart, (float*)d_out);
}